// Round 4
// baseline (688.956 us; speedup 1.0000x reference)
//
#include <hip/hip_runtime.h>
#include <hip/hip_bf16.h>
#include <stdint.h>

// Problem constants: B=4,S=2048 -> T=8192 rows; IN=OUT=4096; CODESZ=8; NCODES=256
#define T_ROWS 8192
#define N_IN   4096
#define N_OUT  4096

typedef __attribute__((ext_vector_type(4))) float f32x4;
typedef __attribute__((ext_vector_type(8))) short bf16x8;

__device__ __forceinline__ unsigned short f2bf(float x) {
  union { float f; unsigned u; } v; v.f = x;
  unsigned r = v.u + 0x7fffu + ((v.u >> 16) & 1u);  // round-nearest-even
  return (unsigned short)(r >> 16);
}

// ---------------- K0: input f32 -> bf16 (A operand) ----------------
__global__ __launch_bounds__(256) void k_cvt(const float* __restrict__ x,
                                             unsigned short* __restrict__ a,
                                             int n8) {
  int stride = gridDim.x * blockDim.x;
  for (int p = blockIdx.x * blockDim.x + threadIdx.x; p < n8; p += stride) {
    const float4* src = (const float4*)(x + (size_t)p * 8);
    float4 v0 = src[0];
    float4 v1 = src[1];
    uint4 w;
    w.x = (unsigned)f2bf(v0.x) | ((unsigned)f2bf(v0.y) << 16);
    w.y = (unsigned)f2bf(v0.z) | ((unsigned)f2bf(v0.w) << 16);
    w.z = (unsigned)f2bf(v1.x) | ((unsigned)f2bf(v1.y) << 16);
    w.w = (unsigned)f2bf(v1.z) | ((unsigned)f2bf(v1.w) << 16);
    *(uint4*)(a + (size_t)p * 8) = w;
  }
}

// ---------------- K1: decode W row + unnormalized FWHT along IN ----------------
// One block per output row o. Codebook (8KB) staged in LDS. First 4 FWHT stages
// (h=1..8) done in registers on the 16 contiguous elems of 2 codewords.
__global__ __launch_bounds__(256) void k_decode_rowfwht(
    const int* __restrict__ Qidxs, const float* __restrict__ codebook,
    float* __restrict__ U) {
  __shared__ float row[4096];
  __shared__ float cb[2048];
  int o = blockIdx.x;
  int t = threadIdx.x;
  for (int i = t; i < 2048; i += 256) cb[i] = codebook[i];
  __syncthreads();
  const int* q = Qidxs + (size_t)o * 512;
  int i0 = q[t * 2], i1 = q[t * 2 + 1];
  float v[16];
#pragma unroll
  for (int j = 0; j < 8; ++j) v[j] = cb[i0 * 8 + j];
#pragma unroll
  for (int j = 0; j < 8; ++j) v[8 + j] = cb[i1 * 8 + j];
  // in-register stages h = 1,2,4,8 (chunk base 16t is 16-aligned)
#pragma unroll
  for (int h = 1; h < 16; h <<= 1) {
#pragma unroll
    for (int b = 0; b < 8; ++b) {
      int i = ((b & ~(h - 1)) << 1) | (b & (h - 1));
      float a = v[i], d = v[i + h];
      v[i] = a + d; v[i + h] = a - d;
    }
  }
#pragma unroll
  for (int j = 0; j < 16; ++j) row[t * 16 + j] = v[j];
  __syncthreads();
  // LDS stages h = 16..2048
  for (int h = 16; h < 4096; h <<= 1) {
#pragma unroll
    for (int bb = 0; bb < 8; ++bb) {
      int b = t + bb * 256;
      int i = ((b & ~(h - 1)) << 1) | (b & (h - 1));
      float a = row[i], d = row[i + h];
      row[i] = a + d; row[i + h] = a - d;
    }
    __syncthreads();
  }
  float4* dst = (float4*)(U + (size_t)o * 4096);
  for (int i = t; i < 1024; i += 256) dst[i] = *(float4*)(row + i * 4);
}

// ---------------- K2: column FWHT, stage over o1 (rows o0 + 64*o1) ----------------
// H_4096 = H_64 (x) H_64 over the OUT axis; this kernel does the stride-64 factor.
__global__ __launch_bounds__(256) void k_colfwht_s(float* __restrict__ U) {
  __shared__ float tile[64][65];
  int bx = blockIdx.x;
  int o0 = bx & 63;
  int j0 = (bx >> 6) << 6;
  int t = threadIdx.x;
#pragma unroll
  for (int qq = 0; qq < 16; ++qq) {
    int idx = t + qq * 256;
    int r = idx >> 6, c = idx & 63;
    tile[r][c] = U[(size_t)(o0 + (r << 6)) * 4096 + j0 + c];
  }
  __syncthreads();
  int c = t & 63, bg = t >> 6;
  for (int h = 1; h < 64; h <<= 1) {
#pragma unroll
    for (int s = 0; s < 8; ++s) {
      int b = bg * 8 + s;
      int i = ((b & ~(h - 1)) << 1) | (b & (h - 1));
      float a = tile[i][c], d = tile[i + h][c];
      tile[i][c] = a + d; tile[i + h][c] = a - d;
    }
    __syncthreads();
  }
#pragma unroll
  for (int qq = 0; qq < 16; ++qq) {
    int idx = t + qq * 256;
    int r = idx >> 6, c2 = idx & 63;
    U[(size_t)(o0 + (r << 6)) * 4096 + j0 + c2] = tile[r][c2];
  }
}

// ---------------- K3: column FWHT stage over o0 (contiguous) + scale + bf16 ----------------
__global__ __launch_bounds__(256) void k_colfwht_c(
    const float* __restrict__ U, const float* __restrict__ SU,
    const float* __restrict__ SV, const float* __restrict__ Wscale,
    unsigned short* __restrict__ Mt) {
  __shared__ float tile[64][65];
  int bx = blockIdx.x;
  int ob = (bx & 63) << 6;          // contiguous 64-row band
  int j0 = (bx >> 6) << 6;
  int t = threadIdx.x;
#pragma unroll
  for (int qq = 0; qq < 16; ++qq) {
    int idx = t + qq * 256;
    int r = idx >> 6, c = idx & 63;
    tile[r][c] = U[(size_t)(ob + r) * 4096 + j0 + c];
  }
  __syncthreads();
  int c = t & 63, bg = t >> 6;
  for (int h = 1; h < 64; h <<= 1) {
#pragma unroll
    for (int s = 0; s < 8; ++s) {
      int b = bg * 8 + s;
      int i = ((b & ~(h - 1)) << 1) | (b & (h - 1));
      float a = tile[i][c], d = tile[i + h][c];
      tile[i][c] = a + d; tile[i + h][c] = a - d;
    }
    __syncthreads();
  }
  float ws = Wscale[0] * (1.0f / 4096.0f);
#pragma unroll
  for (int qq = 0; qq < 16; ++qq) {
    int idx = t + qq * 256;
    int r = idx >> 6, c2 = idx & 63;
    float val = tile[r][c2] * SU[j0 + c2] * (SV[ob + r] * ws);
    Mt[(size_t)(ob + r) * 4096 + j0 + c2] = f2bf(val);
  }
}

// ---------------- K4: GEMM y[t][o] = sum_j A[t][j] * Mt[o][j] ----------------
// m97 structure: 128x128 tile, BK=32, 4 waves (2x2), 4x4 mfma_16x16x32_bf16/wave,
// global_load_lds width-16 staging, XCD-aware block swizzle.
#define BM 128
#define BN 128
#define BK 32

__device__ __forceinline__ void gload_lds16(const void* g, void* l) {
  __builtin_amdgcn_global_load_lds(
      (const __attribute__((address_space(1))) void*)g,
      (__attribute__((address_space(3))) void*)l, 16, 0, 0);
}

__global__ __launch_bounds__(256) void k_gemm(
    const unsigned short* __restrict__ A,   // [8192][4096] bf16
    const unsigned short* __restrict__ B,   // [4096][4096] bf16 (Mt, K-major)
    float* __restrict__ C) {                // [8192][4096] f32
  __shared__ unsigned short As[BM * BK];    // 8KB, row-major [128][32]
  __shared__ unsigned short Bs[BN * BK];    // 8KB
  int tid = threadIdx.x;
  int lane = tid & 63;
  int wave = tid >> 6;
  int wr = wave >> 1, wc = wave & 1;

  // XCD-bijective swizzle: 2048 blocks, 8 XCDs -> 256 contiguous tiles per XCD
  int bid = blockIdx.x;
  int swz = (bid & 7) * 256 + (bid >> 3);
  int bm = swz >> 5;    // 64 M-tiles
  int bn = swz & 31;    // 32 N-tiles

  const unsigned short* Abase = A + (size_t)(bm * BM) * N_IN;
  const unsigned short* Bbase = B + (size_t)(bn * BN) * N_IN;

  int sRow = tid >> 2;           // 0..63 (staging row)
  int sCol = (tid & 3) * 8;      // 0,8,16,24 (staging k)

  f32x4 acc[4][4];
#pragma unroll
  for (int m = 0; m < 4; ++m)
#pragma unroll
    for (int n = 0; n < 4; ++n)
      acc[m][n] = (f32x4){0.f, 0.f, 0.f, 0.f};

  int koff = (lane >> 4) * 8;          // fragment k offset (contiguous 8)
  int arow = wr * 64 + (lane & 15);    // + m*16
  int brow = wc * 64 + (lane & 15);    // + n*16

  for (int k0 = 0; k0 < N_IN; k0 += BK) {
    gload_lds16(Abase + (size_t)sRow * N_IN + k0 + sCol,        As + tid * 8);
    gload_lds16(Abase + (size_t)(sRow + 64) * N_IN + k0 + sCol, As + 2048 + tid * 8);
    gload_lds16(Bbase + (size_t)sRow * N_IN + k0 + sCol,        Bs + tid * 8);
    gload_lds16(Bbase + (size_t)(sRow + 64) * N_IN + k0 + sCol, Bs + 2048 + tid * 8);
    __syncthreads();   // compiler emits vmcnt(0) drain before barrier
    bf16x8 af[4], bfr[4];
#pragma unroll
    for (int m = 0; m < 4; ++m)
      af[m] = *(const bf16x8*)(As + (arow + m * 16) * BK + koff);
#pragma unroll
    for (int n = 0; n < 4; ++n)
      bfr[n] = *(const bf16x8*)(Bs + (brow + n * 16) * BK + koff);
#pragma unroll
    for (int m = 0; m < 4; ++m)
#pragma unroll
      for (int n = 0; n < 4; ++n)
        acc[m][n] = __builtin_amdgcn_mfma_f32_16x16x32_bf16(af[m], bfr[n], acc[m][n], 0, 0, 0);
    __syncthreads();
  }

  // Epilogue: D layout col = lane&15, row = (lane>>4)*4 + reg (m89-verified)
  int crow0 = bm * BM + wr * 64 + (lane >> 4) * 4;
  int ccol0 = bn * BN + wc * 64 + (lane & 15);
#pragma unroll
  for (int m = 0; m < 4; ++m)
#pragma unroll
    for (int n = 0; n < 4; ++n) {
      float* cp = C + (size_t)(crow0 + m * 16) * N_OUT + ccol0 + n * 16;
#pragma unroll
      for (int r = 0; r < 4; ++r)
        cp[(size_t)r * N_OUT] = acc[m][n][r];
    }
}

extern "C" void kernel_launch(void* const* d_in, const int* in_sizes, int n_in,
                              void* d_out, int out_size, void* d_ws, size_t ws_size,
                              hipStream_t stream) {
  const float* input    = (const float*)d_in[0];
  const int*   Qidxs    = (const int*)d_in[1];
  const float* codebook = (const float*)d_in[2];
  const float* SU       = (const float*)d_in[3];
  const float* SV       = (const float*)d_in[4];
  const float* Wscale   = (const float*)d_in[5];
  float* out = (float*)d_out;

  // ws layout: [0,64MB): U (f32 4096x4096), later reused as A (bf16 8192x4096)
  //            [64MB,96MB): Mt (bf16 4096x4096)
  float*          U   = (float*)d_ws;
  unsigned short* Abf = (unsigned short*)d_ws;
  unsigned short* Mt  = (unsigned short*)((char*)d_ws + (((size_t)64) << 20));

  hipLaunchKernelGGL(k_decode_rowfwht, dim3(4096), dim3(256), 0, stream, Qidxs, codebook, U);
  hipLaunchKernelGGL(k_colfwht_s,      dim3(4096), dim3(256), 0, stream, U);
  hipLaunchKernelGGL(k_colfwht_c,      dim3(4096), dim3(256), 0, stream, U, SU, SV, Wscale, Mt);
  hipLaunchKernelGGL(k_cvt,            dim3(2048), dim3(256), 0, stream, input, Abf,
                     (T_ROWS * N_IN) / 8);
  hipLaunchKernelGGL(k_gemm,           dim3(2048), dim3(256), 0, stream, Abf, Mt, out);
}

// Round 5
// 519.192 us; speedup vs baseline: 1.3270x; 1.3270x over previous
//
#include <hip/hip_runtime.h>
#include <hip/hip_bf16.h>
#include <stdint.h>

// Problem constants: B=4,S=2048 -> T=8192 rows; IN=OUT=4096; CODESZ=8; NCODES=256
#define T_ROWS 8192
#define N_IN   4096
#define N_OUT  4096

typedef __attribute__((ext_vector_type(4))) float f32x4;
typedef __attribute__((ext_vector_type(8))) short bf16x8;
typedef __attribute__((ext_vector_type(4))) unsigned short u16x4;

__device__ __forceinline__ unsigned short f2bf(float x) {
  union { float f; unsigned u; } v; v.f = x;
  unsigned r = v.u + 0x7fffu + ((v.u >> 16) & 1u);  // round-nearest-even
  return (unsigned short)(r >> 16);
}

// ---------------- K0: input f32 -> bf16 (A operand) ----------------
__global__ __launch_bounds__(256) void k_cvt(const float* __restrict__ x,
                                             unsigned short* __restrict__ a,
                                             int n8) {
  int stride = gridDim.x * blockDim.x;
  for (int p = blockIdx.x * blockDim.x + threadIdx.x; p < n8; p += stride) {
    const float4* src = (const float4*)(x + (size_t)p * 8);
    float4 v0 = src[0];
    float4 v1 = src[1];
    uint4 w;
    w.x = (unsigned)f2bf(v0.x) | ((unsigned)f2bf(v0.y) << 16);
    w.y = (unsigned)f2bf(v0.z) | ((unsigned)f2bf(v0.w) << 16);
    w.z = (unsigned)f2bf(v1.x) | ((unsigned)f2bf(v1.y) << 16);
    w.w = (unsigned)f2bf(v1.z) | ((unsigned)f2bf(v1.w) << 16);
    *(uint4*)(a + (size_t)p * 8) = w;
  }
}

// ---------------- K1: decode W row + unnormalized FWHT along IN ----------------
// Codebook staged TRANSPOSED in LDS (cbT[j][code], stride 257) so the random
// gather cbT[j*257+code] spreads across all 32 banks (~2-way, free) instead of
// the 16-way conflict of cb[code*8+j] (banks limited to {j mod 8 + 8k}).
__global__ __launch_bounds__(256) void k_decode_rowfwht(
    const int* __restrict__ Qidxs, const float* __restrict__ codebook,
    float* __restrict__ U) {
  __shared__ float row[4096];
  __shared__ float cbT[8 * 257];
  int o = blockIdx.x;
  int t = threadIdx.x;
  for (int i = t; i < 2048; i += 256) cbT[(i & 7) * 257 + (i >> 3)] = codebook[i];
  __syncthreads();
  const int* q = Qidxs + (size_t)o * 512;
  int i0 = q[t * 2], i1 = q[t * 2 + 1];
  float v[16];
#pragma unroll
  for (int j = 0; j < 8; ++j) v[j] = cbT[j * 257 + i0];
#pragma unroll
  for (int j = 0; j < 8; ++j) v[8 + j] = cbT[j * 257 + i1];
  // in-register stages h = 1,2,4,8 (chunk base 16t is 16-aligned)
#pragma unroll
  for (int h = 1; h < 16; h <<= 1) {
#pragma unroll
    for (int b = 0; b < 8; ++b) {
      int i = ((b & ~(h - 1)) << 1) | (b & (h - 1));
      float a = v[i], d = v[i + h];
      v[i] = a + d; v[i + h] = a - d;
    }
  }
#pragma unroll
  for (int j = 0; j < 16; ++j) row[t * 16 + j] = v[j];
  __syncthreads();
  // LDS stages h = 16..2048
  for (int h = 16; h < 4096; h <<= 1) {
#pragma unroll
    for (int bb = 0; bb < 8; ++bb) {
      int b = t + bb * 256;
      int i = ((b & ~(h - 1)) << 1) | (b & (h - 1));
      float a = row[i], d = row[i + h];
      row[i] = a + d; row[i + h] = a - d;
    }
    __syncthreads();
  }
  float4* dst = (float4*)(U + (size_t)o * 4096);
  for (int i = t; i < 1024; i += 256) dst[i] = *(float4*)(row + i * 4);
}

// ---------------- K2: column FWHT, stride-64 H64 factor (float4 vectorized) ----
// tile stride 68 floats: 16B-aligned rows (68*4=272B) and conflict-free columns.
__global__ __launch_bounds__(256) void k_colfwht_s(float* __restrict__ U) {
  __shared__ float tile[64 * 68];
  int bx = blockIdx.x;
  int o0 = bx & 63;
  int j0 = (bx >> 6) << 6;
  int t = threadIdx.x;
#pragma unroll
  for (int qq = 0; qq < 4; ++qq) {
    int idx = t + qq * 256;
    int r = idx >> 4, c4 = (idx & 15) << 2;
    *(float4*)&tile[r * 68 + c4] =
        *(const float4*)&U[(size_t)(o0 + (r << 6)) * 4096 + j0 + c4];
  }
  __syncthreads();
  int c = t & 63, bg = t >> 6;
  for (int h = 1; h < 64; h <<= 1) {
#pragma unroll
    for (int s = 0; s < 8; ++s) {
      int b = bg * 8 + s;
      int i = ((b & ~(h - 1)) << 1) | (b & (h - 1));
      float a = tile[i * 68 + c], d = tile[(i + h) * 68 + c];
      tile[i * 68 + c] = a + d; tile[(i + h) * 68 + c] = a - d;
    }
    __syncthreads();
  }
#pragma unroll
  for (int qq = 0; qq < 4; ++qq) {
    int idx = t + qq * 256;
    int r = idx >> 4, c4 = (idx & 15) << 2;
    *(float4*)&U[(size_t)(o0 + (r << 6)) * 4096 + j0 + c4] =
        *(float4*)&tile[r * 68 + c4];
  }
}

// ---------------- K3: column FWHT contiguous H64 factor + scale + bf16 --------
__global__ __launch_bounds__(256) void k_colfwht_c(
    const float* __restrict__ U, const float* __restrict__ SU,
    const float* __restrict__ SV, const float* __restrict__ Wscale,
    unsigned short* __restrict__ Mt) {
  __shared__ float tile[64 * 68];
  int bx = blockIdx.x;
  int ob = (bx & 63) << 6;          // contiguous 64-row band
  int j0 = (bx >> 6) << 6;
  int t = threadIdx.x;
#pragma unroll
  for (int qq = 0; qq < 4; ++qq) {
    int idx = t + qq * 256;
    int r = idx >> 4, c4 = (idx & 15) << 2;
    *(float4*)&tile[r * 68 + c4] =
        *(const float4*)&U[(size_t)(ob + r) * 4096 + j0 + c4];
  }
  __syncthreads();
  int c = t & 63, bg = t >> 6;
  for (int h = 1; h < 64; h <<= 1) {
#pragma unroll
    for (int s = 0; s < 8; ++s) {
      int b = bg * 8 + s;
      int i = ((b & ~(h - 1)) << 1) | (b & (h - 1));
      float a = tile[i * 68 + c], d = tile[(i + h) * 68 + c];
      tile[i * 68 + c] = a + d; tile[(i + h) * 68 + c] = a - d;
    }
    __syncthreads();
  }
  float ws = Wscale[0] * (1.0f / 4096.0f);
#pragma unroll
  for (int qq = 0; qq < 4; ++qq) {
    int idx = t + qq * 256;
    int r = idx >> 4, c4 = (idx & 15) << 2;
    float4 v = *(float4*)&tile[r * 68 + c4];
    float4 su = *(const float4*)&SU[j0 + c4];
    float sv = SV[ob + r] * ws;
    u16x4 w;
    w.x = f2bf(v.x * su.x * sv);
    w.y = f2bf(v.y * su.y * sv);
    w.z = f2bf(v.z * su.z * sv);
    w.w = f2bf(v.w * su.w * sv);
    *(u16x4*)&Mt[(size_t)(ob + r) * 4096 + j0 + c4] = w;
  }
}

// ---------------- K4: GEMM y[t][o] = sum_j A[t][j] * Mt[o][j] -----------------
// Ring-4 K-tile pipeline (T3+T4): 256x256 tile, BK=32, 8 waves (2M x 4N),
// 4 x 32KB LDS buffers. Per tile: vmcnt(8) [3 tiles of loads in flight, never
// 0] + ONE raw s_barrier; stage tile t+3 into the buffer tile t-1 finished
// with (race-free: its readers' lgkm drained before the barrier preceding the
// stage issue); 12 swizzled ds_read_b128; 32 MFMA under setprio(1).
// LDS swizzle: 16B slot s at row r holds logical k-block s^(r&3); staging
// inverse-swizzles the GLOBAL source (rule #21), gload_lds dest stays linear.
#define GBK 32
#define GNT 128   // 4096/32 K-tiles

__device__ __forceinline__ void gload16(const unsigned short* g, unsigned short* l) {
  __builtin_amdgcn_global_load_lds(
      (const __attribute__((address_space(1))) void*)g,
      (__attribute__((address_space(3))) void*)l, 16, 0, 0);
}

__global__ __launch_bounds__(512, 1) void k_gemm2(
    const unsigned short* __restrict__ A,   // [8192][4096] bf16
    const unsigned short* __restrict__ B,   // [4096][4096] bf16 (Mt, K-major)
    float* __restrict__ C) {                // [8192][4096] f32
  __shared__ unsigned short lds[4 * 16384];   // 4 bufs x (A 16KB + B 16KB) = 128KB
  int tid = threadIdx.x;
  int lane = tid & 63;
  int w = tid >> 6;                 // 8 waves
  int wm = w >> 2, wn = w & 3;      // 2 x 4 wave grid

  // XCD-bijective swizzle: 512 blocks, 8 XCDs -> 64 contiguous tiles per XCD
  int bid = blockIdx.x;
  int swz = (bid & 7) * 64 + (bid >> 3);
  int bm = swz >> 4;                // 32 M-tiles
  int bn = swz & 15;                // 16 N-tiles

  const unsigned short* gA = A + (size_t)(bm * 256) * N_IN;
  const unsigned short* gB = B + (size_t)(bn * 256) * N_IN;

  // staging: per round, wave w covers 16 rows (lane>>2), 4 x 16B slots (lane&3)
  int srow = w * 16 + (lane >> 2);
  int scb  = ((lane & 3) ^ ((lane >> 2) & 3)) * 8;   // inverse-swizzled k-block
  const unsigned short* sA = gA + (size_t)srow * N_IN + scb;
  const unsigned short* sB = gB + (size_t)srow * N_IN + scb;
  unsigned short* sD = lds + w * 512 + lane * 8;     // + q*16384 per tile

  // fragment-read bases (shorts): slot8 = swizzled 16B slot for this lane
  int slot8 = (((lane >> 4) ^ (lane & 3))) * 8;
  int arow32 = (wm * 64 + (lane & 15)) * 32 + slot8;
  int brow32 = (wn * 32 + (lane & 15)) * 32 + slot8 + 8192;

  f32x4 acc[8][4];
#pragma unroll
  for (int i = 0; i < 8; ++i)
#pragma unroll
    for (int j = 0; j < 4; ++j) acc[i][j] = (f32x4){0.f, 0.f, 0.f, 0.f};

#define STAGE(tt) { \
    unsigned short* d = sD + ((tt) & 3) * 16384; \
    int k0 = (tt) * GBK; \
    gload16(sA + k0, d); \
    gload16(sA + (size_t)128 * N_IN + k0, d + 4096); \
    gload16(sB + k0, d + 8192); \
    gload16(sB + (size_t)128 * N_IN + k0, d + 12288); \
  }

#define TILE_TOP(VMC) \
    asm volatile("s_waitcnt vmcnt(" #VMC ")" ::: "memory"); \
    __builtin_amdgcn_s_barrier(); \
    asm volatile("" ::: "memory");

#define COMPUTE(tt) { \
    const unsigned short* Lq = lds + ((tt) & 3) * 16384; \
    bf16x8 b0 = *(const bf16x8*)(Lq + brow32); \
    bf16x8 b1 = *(const bf16x8*)(Lq + brow32 + 512); \
    bf16x8 b2 = *(const bf16x8*)(Lq + brow32 + 4096); \
    bf16x8 b3 = *(const bf16x8*)(Lq + brow32 + 4608); \
    bf16x8 a0 = *(const bf16x8*)(Lq + arow32); \
    bf16x8 a1 = *(const bf16x8*)(Lq + arow32 + 512); \
    bf16x8 a2 = *(const bf16x8*)(Lq + arow32 + 1024); \
    bf16x8 a3 = *(const bf16x8*)(Lq + arow32 + 1536); \
    __builtin_amdgcn_s_setprio(1); \
    acc[0][0] = __builtin_amdgcn_mfma_f32_16x16x32_bf16(a0, b0, acc[0][0], 0, 0, 0); \
    acc[0][1] = __builtin_amdgcn_mfma_f32_16x16x32_bf16(a0, b1, acc[0][1], 0, 0, 0); \
    acc[0][2] = __builtin_amdgcn_mfma_f32_16x16x32_bf16(a0, b2, acc[0][2], 0, 0, 0); \
    acc[0][3] = __builtin_amdgcn_mfma_f32_16x16x32_bf16(a0, b3, acc[0][3], 0, 0, 0); \
    acc[1][0] = __builtin_amdgcn_mfma_f32_16x16x32_bf16(a1, b0, acc[1][0], 0, 0, 0); \
    acc[1][1] = __builtin_amdgcn_mfma_f32_16x16x32_bf16(a1, b1, acc[1][1], 0, 0, 0); \
    acc[1][2] = __builtin_amdgcn_mfma_f32_16x16x32_bf16(a1, b2, acc[1][2], 0, 0, 0); \
    acc[1][3] = __builtin_amdgcn_mfma_f32_16x16x32_bf16(a1, b3, acc[1][3], 0, 0, 0); \
    acc[2][0] = __builtin_amdgcn_mfma_f32_16x16x32_bf16(a2, b0, acc[2][0], 0, 0, 0); \
    acc[2][1] = __builtin_amdgcn_mfma_f32_16x16x32_bf16(a2, b1, acc[2][1], 0, 0, 0); \
    acc[2][2] = __builtin_amdgcn_mfma_f32_16x16x32_bf16(a2, b2, acc[2][2], 0, 0, 0); \
    acc[2][3] = __builtin_amdgcn_mfma_f32_16x16x32_bf16(a2, b3, acc[2][3], 0, 0, 0); \
    acc[3][0] = __builtin_amdgcn_mfma_f32_16x16x32_bf16(a3, b0, acc[3][0], 0, 0, 0); \
    acc[3][1] = __builtin_amdgcn_mfma_f32_16x16x32_bf16(a3, b1, acc[3][1], 0, 0, 0); \
    acc[3][2] = __builtin_amdgcn_mfma_f32_16x16x32_bf16(a3, b2, acc[3][2], 0, 0, 0); \
    acc[3][3] = __builtin_amdgcn_mfma_f32_16x16x32_bf16(a3, b3, acc[3][3], 0, 0, 0); \
    __builtin_amdgcn_s_setprio(0); \
    a0 = *(const bf16x8*)(Lq + arow32 + 4096); \
    a1 = *(const bf16x8*)(Lq + arow32 + 4608); \
    a2 = *(const bf16x8*)(Lq + arow32 + 5120); \
    a3 = *(const bf16x8*)(Lq + arow32 + 5632); \
    __builtin_amdgcn_s_setprio(1); \
    acc[4][0] = __builtin_amdgcn_mfma_f32_16x16x32_bf16(a0, b0, acc[4][0], 0, 0, 0); \
    acc[4][1] = __builtin_amdgcn_mfma_f32_16x16x32_bf16(a0, b1, acc[4][1], 0, 0, 0); \
    acc[4][2] = __builtin_amdgcn_mfma_f32_16x16x32_bf16(a0, b2, acc[4][2], 0, 0, 0); \
    acc[4][3] = __builtin_amdgcn_mfma_f32_16x16x32_bf16(a0, b3, acc[4][3], 0, 0, 0); \
    acc[5][0] = __builtin_amdgcn_mfma_f32_16x16x32_bf16(a1, b0, acc[5][0], 0, 0, 0); \
    acc[5][1] = __builtin_amdgcn_mfma_f32_16x16x32_bf16(a1, b1, acc[5][1], 0, 0, 0); \
    acc[5][2] = __builtin_amdgcn_mfma_f32_16x16x32_bf16(a1, b2, acc[5][2], 0, 0, 0); \
    acc[5][3] = __builtin_amdgcn_mfma_f32_16x16x32_bf16(a1, b3, acc[5][3], 0, 0, 0); \
    acc[6][0] = __builtin_amdgcn_mfma_f32_16x16x32_bf16(a2, b0, acc[6][0], 0, 0, 0); \
    acc[6][1] = __builtin_amdgcn_mfma_f32_16x16x32_bf16(a2, b1, acc[6][1], 0, 0, 0); \
    acc[6][2] = __builtin_amdgcn_mfma_f32_16x16x32_bf16(a2, b2, acc[6][2], 0, 0, 0); \
    acc[6][3] = __builtin_amdgcn_mfma_f32_16x16x32_bf16(a2, b3, acc[6][3], 0, 0, 0); \
    acc[7][0] = __builtin_amdgcn_mfma_f32_16x16x32_bf16(a3, b0, acc[7][0], 0, 0, 0); \
    acc[7][1] = __builtin_amdgcn_mfma_f32_16x16x32_bf16(a3, b1, acc[7][1], 0, 0, 0); \
    acc[7][2] = __builtin_amdgcn_mfma_f32_16x16x32_bf16(a3, b2, acc[7][2], 0, 0, 0); \
    acc[7][3] = __builtin_amdgcn_mfma_f32_16x16x32_bf16(a3, b3, acc[7][3], 0, 0, 0); \
    __builtin_amdgcn_s_setprio(0); \
  }

  // prologue: 3 tiles in flight
  STAGE(0); STAGE(1); STAGE(2);
#pragma unroll 4
  for (int t = 0; t < GNT - 3; ++t) {    // t = 0..124, stages tiles 3..127
    TILE_TOP(8);
    STAGE(t + 3);
    COMPUTE(t);
  }
  TILE_TOP(8); COMPUTE(GNT - 3);
  TILE_TOP(4); COMPUTE(GNT - 2);
  TILE_TOP(0); COMPUTE(GNT - 1);

  // Epilogue: D layout col = lane&15, row = (lane>>4)*4 + reg (m89-verified)
#pragma unroll
  for (int i = 0; i < 8; ++i) {
    int crow0 = bm * 256 + (i >> 2) * 128 + wm * 64 + (i & 3) * 16 + (lane >> 4) * 4;
#pragma unroll
    for (int j = 0; j < 4; ++j) {
      int ccol = bn * 256 + (j >> 1) * 128 + wn * 32 + (j & 1) * 16 + (lane & 15);
      float* cp = C + (size_t)crow0 * N_OUT + ccol;
#pragma unroll
      for (int r = 0; r < 4; ++r)
        cp[(size_t)r * N_OUT] = acc[i][j][r];
    }
  }
#undef STAGE
#undef TILE_TOP
#undef COMPUTE
}

extern "C" void kernel_launch(void* const* d_in, const int* in_sizes, int n_in,
                              void* d_out, int out_size, void* d_ws, size_t ws_size,
                              hipStream_t stream) {
  const float* input    = (const float*)d_in[0];
  const int*   Qidxs    = (const int*)d_in[1];
  const float* codebook = (const float*)d_in[2];
  const float* SU       = (const float*)d_in[3];
  const float* SV       = (const float*)d_in[4];
  const float* Wscale   = (const float*)d_in[5];
  float* out = (float*)d_out;

  // ws layout: [0,64MB): U (f32 4096x4096), later reused as A (bf16 8192x4096)
  //            [64MB,96MB): Mt (bf16 4096x4096)
  float*          U   = (float*)d_ws;
  unsigned short* Abf = (unsigned short*)d_ws;
  unsigned short* Mt  = (unsigned short*)((char*)d_ws + (((size_t)64) << 20));

  hipLaunchKernelGGL(k_decode_rowfwht, dim3(4096), dim3(256), 0, stream, Qidxs, codebook, U);
  hipLaunchKernelGGL(k_colfwht_s,      dim3(4096), dim3(256), 0, stream, U);
  hipLaunchKernelGGL(k_colfwht_c,      dim3(4096), dim3(256), 0, stream, U, SU, SV, Wscale, Mt);
  hipLaunchKernelGGL(k_cvt,            dim3(2048), dim3(256), 0, stream, input, Abf,
                     (T_ROWS * N_IN) / 8);
  hipLaunchKernelGGL(k_gemm2,          dim3(512), dim3(512), 0, stream, Abf, Mt, out);
}